// Round 5
// baseline (552.255 us; speedup 1.0000x reference)
//
#include <hip/hip_runtime.h>
#include <math.h>

#define SLICES     8
#define SLICE_CAP  512     // per-slice candidate capacity in ws
#define K1_BLOCK   256
#define K2_BLOCK   256
#define MAXNI      8       // K1 register stash: supports slice_len <= 8192 (d <= 65536) in-register
#define FCAP       6144    // K2 final candidate array (24 KB LDS)
#define NREG       12      // wave0 register-resident candidates: 64*12 = 768

__device__ __forceinline__ float waveReduceMax(float v) {
#pragma unroll
    for (int off = 32; off > 0; off >>= 1)
        v = fmaxf(v, __shfl_down(v, off, 64));
    return v;
}
__device__ __forceinline__ float waveReduceSum(float v) {
#pragma unroll
    for (int off = 32; off > 0; off >>= 1)
        v += __shfl_down(v, off, 64);
    return v;
}

// ---------------- Kernel 1: slice max + superset filter (the ONE HBM pass) --
// 8 blocks per row. Candidates x >= slicemax-2 are a superset of the true
// support {x >= rowmax-2} because slicemax <= rowmax and tau* in [-1,0] in
// u=(x-rowmax)/2 units. Raw x values stored; exact prune happens in K2.
__global__ __launch_bounds__(K1_BLOCK, 4) void k1_filter(
    const float* __restrict__ x, float* __restrict__ cand,
    int* __restrict__ cnt, float* __restrict__ smax,
    int d, int slice_len, int ni)
{
    __shared__ float s_red[K1_BLOCK / 64];
    __shared__ int   s_cnt;
    __shared__ float s_c[SLICE_CAP];
    __shared__ float s_bmax;

    const int sid  = blockIdx.x;
    const int row  = sid >> 3;
    const int sl   = sid & 7;
    const int t    = threadIdx.x;
    const int lane = t & 63;
    const int wave = t >> 6;

    if (t == 0) s_cnt = 0;

    const int sbeg = sl * slice_len;
    const int send = min(sbeg + slice_len, d);
    const float* __restrict__ xr = x + (size_t)row * (size_t)d;

    float4 c[MAXNI];
#pragma unroll
    for (int i = 0; i < MAXNI; ++i)
        c[i] = make_float4(-INFINITY, -INFINITY, -INFINITY, -INFINITY);

    float m = -INFINITY;
    // max phase (stash first MAXNI chunks in registers)
    for (int i = 0; i < ni; ++i) {
        int p = sbeg + (i * K1_BLOCK + t) * 4;
        float4 v = make_float4(-INFINITY, -INFINITY, -INFINITY, -INFINITY);
        if (p + 4 <= send) {
            v = *reinterpret_cast<const float4*>(xr + p);
        } else if (p < send) {
            v.x = xr[p];
            if (p + 1 < send) v.y = xr[p + 1];
            if (p + 2 < send) v.z = xr[p + 2];
        }
        if (i < MAXNI) c[i] = v;
        m = fmaxf(m, fmaxf(fmaxf(v.x, v.y), fmaxf(v.z, v.w)));
    }
    m = waveReduceMax(m);
    if (lane == 0) s_red[wave] = m;
    __syncthreads();
    if (t == 0) {
        float v = s_red[0];
#pragma unroll
        for (int w = 1; w < K1_BLOCK / 64; ++w) v = fmaxf(v, s_red[w]);
        s_bmax = v;
    }
    __syncthreads();
    const float mx  = s_bmax;
    const float thr = mx - 2.0f;

    // filter phase: registers for i < MAXNI, L2-warm reload beyond (generic path)
    for (int i = 0; i < ni; ++i) {
        float4 v;
        if (i < MAXNI) {
            v = c[i];
        } else {
            int p = sbeg + (i * K1_BLOCK + t) * 4;
            v = make_float4(-INFINITY, -INFINITY, -INFINITY, -INFINITY);
            if (p + 4 <= send) v = *reinterpret_cast<const float4*>(xr + p);
            else if (p < send) {
                v.x = xr[p];
                if (p + 1 < send) v.y = xr[p + 1];
                if (p + 2 < send) v.z = xr[p + 2];
            }
        }
        float vals[4] = { v.x, v.y, v.z, v.w };
#pragma unroll
        for (int s = 0; s < 4; ++s) {
            float w = vals[s];
            bool pred = (w >= thr);
            unsigned long long mask = __ballot(pred);
            if (mask) {                         // wave-uniform
                int base;
                if (lane == 0) base = atomicAdd(&s_cnt, (int)__popcll(mask));
                base = __shfl(base, 0, 64);
                if (pred) {
                    int pos = base + (int)__popcll(mask & ((1ull << lane) - 1ull));
                    if (pos < SLICE_CAP) s_c[pos] = w;
                }
            }
        }
    }
    __syncthreads();

    const int total = s_cnt;
    if (t == 0) { cnt[sid] = total; smax[sid] = mx; }
    const int wr = min(total, SLICE_CAP);
    for (int j = t; j < wr; j += K1_BLOCK)
        cand[(size_t)sid * SLICE_CAP + j] = s_c[j];
}

// ---------------- Kernel 2: per-row exact prune + solve -----------------
__global__ __launch_bounds__(K2_BLOCK, 4) void k2_solve(
    const float* __restrict__ x, const float* __restrict__ cand,
    const int* __restrict__ cnt, const float* __restrict__ smax,
    const int* __restrict__ tgt, float* __restrict__ out,
    int d, float inv_n)
{
    __shared__ float s_final[FCAP];
    __shared__ int   s_cnt8[SLICES];
    __shared__ int   s_fcnt;
    __shared__ int   s_ovf;
    __shared__ float s_bcast;

    const int row  = blockIdx.x;
    const int t    = threadIdx.x;
    const int lane = t & 63;
    const int wave = t >> 6;

    if (t == 0) { s_fcnt = 0; s_ovf = 0; }

    if (wave == 0) {
        float v = -INFINITY;
        if (lane < SLICES) {
            int c8 = cnt[row * SLICES + lane];
            s_cnt8[lane] = min(c8, SLICE_CAP);
            if (c8 > SLICE_CAP) s_ovf = 1;      // benign multi-writer
            v = smax[row * SLICES + lane];
        }
#pragma unroll
        for (int off = 1; off < SLICES; off <<= 1)
            v = fmaxf(v, __shfl_xor(v, off, 64));
        if (lane == 0) s_bcast = v;
    }
    __syncthreads();
    const float rowmax = s_bcast;
    const float thr    = rowmax - 2.0f;
    const float* __restrict__ xr = x + (size_t)row * (size_t)d;

    if (!s_ovf) {
        // gather compacted candidates (~12 MB total across all rows)
        const float* __restrict__ cr = cand + (size_t)row * SLICES * SLICE_CAP;
        for (int j = t; j < SLICES * SLICE_CAP; j += K2_BLOCK) {
            int slice = j >> 9;                 // SLICE_CAP = 512
            int pos   = j & (SLICE_CAP - 1);
            float v   = cr[j];                  // poison beyond count is masked below
            bool keep = (pos < s_cnt8[slice]) && (v >= thr);
            unsigned long long mask = __ballot(keep);
            if (mask) {
                int base;
                if (lane == 0) base = atomicAdd(&s_fcnt, (int)__popcll(mask));
                base = __shfl(base, 0, 64);
                if (keep) {
                    int p2 = base + (int)__popcll(mask & ((1ull << lane) - 1ull));
                    if (p2 < FCAP) s_final[p2] = (v - rowmax) * 0.5f;
                }
            }
        }
    } else {
        // rare fallback: slice cap overflow -> exact re-stream of the row
        for (int e0 = t * 4; e0 < d; e0 += K2_BLOCK * 4) {
            float4 v = make_float4(-INFINITY, -INFINITY, -INFINITY, -INFINITY);
            if (e0 + 4 <= d) v = *reinterpret_cast<const float4*>(xr + e0);
            else {
                v.x = xr[e0];
                if (e0 + 1 < d) v.y = xr[e0 + 1];
                if (e0 + 2 < d) v.z = xr[e0 + 2];
            }
            float vals[4] = { v.x, v.y, v.z, v.w };
#pragma unroll
            for (int s = 0; s < 4; ++s) {
                float w = vals[s];
                bool keep = (w >= thr);
                unsigned long long mask = __ballot(keep);
                if (mask) {
                    int base;
                    if (lane == 0) base = atomicAdd(&s_fcnt, (int)__popcll(mask));
                    base = __shfl(base, 0, 64);
                    if (keep) {
                        int p2 = base + (int)__popcll(mask & ((1ull << lane) - 1ull));
                        if (p2 < FCAP) s_final[p2] = (w - rowmax) * 0.5f;
                    }
                }
            }
        }
    }
    __syncthreads();

    // ---- wave 0: register-resident root-find + loss (verified, absmax 0.0) ----
    if (wave == 0) {
        const float xt = (lane == 0) ? xr[tgt[row]] : 0.0f;  // hides under bisection

        const int k = min(s_fcnt, FCAP);

        float ur[NREG];
#pragma unroll
        for (int j = 0; j < NREG; ++j) {
            int idx = lane + 64 * j;
            ur[j] = (idx < k) ? s_final[idx] : -1e30f;  // sentinel: never in support
        }

        // bisection: f(tau)=sum max(u-tau,0)^2 monotone dec., f(-1)>=1>=f(0)
        float lo = -1.0f, hi = 0.0f;
        for (int it = 0; it < 18; ++it) {
            float tau = 0.5f * (lo + hi);
            float acc = 0.0f;
#pragma unroll
            for (int j = 0; j < NREG; ++j) {
                float u = ur[j] - tau;
                acc += (u > 0.0f) ? u * u : 0.0f;
            }
            for (int j = 64 * NREG + lane; j < k; j += 64) {  // tail (usually 0-trip)
                float u = s_final[j] - tau;
                if (u > 0.0f) acc += u * u;
            }
            float tot = waveReduceSum(acc);
            tot = __shfl(tot, 0, 64);
            if (tot >= 1.0f) lo = tau; else hi = tau;
        }
        const float tau_b = 0.5f * (lo + hi);

        // exact closed form on identified support: tau* = mean - sqrt((1-ss)/k)
        float s1 = 0.0f, s2 = 0.0f, sc = 0.0f;
#pragma unroll
        for (int j = 0; j < NREG; ++j) {
            float u = ur[j];
            if (u > tau_b) { s1 += u; s2 += u * u; sc += 1.0f; }
        }
        for (int j = 64 * NREG + lane; j < k; j += 64) {
            float u = s_final[j];
            if (u > tau_b) { s1 += u; s2 += u * u; sc += 1.0f; }
        }
        s1 = waveReduceSum(s1); s1 = __shfl(s1, 0, 64);
        s2 = waveReduceSum(s2); s2 = __shfl(s2, 0, 64);
        sc = waveReduceSum(sc); sc = __shfl(sc, 0, 64);
        float mean  = s1 / sc;
        float ss    = s2 - s1 * mean;
        float delta = (1.0f - ss) / sc;
        if (delta < 0.0f) delta = 0.0f;
        const float tau_star = mean - sqrtf(delta);

        // loss: sum p^{3/2} = sum u^3;  dot(p, x) with x = 2u + rowmax
        float p32 = 0.0f, dot = 0.0f;
#pragma unroll
        for (int j = 0; j < NREG; ++j) {
            float u = ur[j] - tau_star;
            if (u > 0.0f) {
                float p = u * u;
                p32 += p * u;
                dot += p * (2.0f * ur[j] + rowmax);
            }
        }
        for (int j = 64 * NREG + lane; j < k; j += 64) {
            float uc = s_final[j];
            float u  = uc - tau_star;
            if (u > 0.0f) {
                float p = u * u;
                p32 += p * u;
                dot += p * (2.0f * uc + rowmax);
            }
        }
        p32 = waveReduceSum(p32);
        dot = waveReduceSum(dot);
        if (lane == 0) {
            float loss = (1.0f - p32) * (4.0f / 3.0f) + dot - xt;
            atomicAdd(out, loss * inv_n);
        }
    }
}

extern "C" void kernel_launch(void* const* d_in, const int* in_sizes, int n_in,
                              void* d_out, int out_size, void* d_ws, size_t ws_size,
                              hipStream_t stream) {
    const float* x   = (const float*)d_in[0];
    const int*   tgt = (const int*)d_in[1];
    float*       out = (float*)d_out;

    const int n = in_sizes[1];
    const int d = in_sizes[0] / n;

    // slice geometry: slice_len multiple of 4 (keeps float4 alignment), 8 slices cover d
    const int slice_len = ((d + 4 * SLICES - 1) / (4 * SLICES)) * 4;
    const int ni        = (slice_len + K1_BLOCK * 4 - 1) / (K1_BLOCK * 4);

    // ws carve: cand | cnt | smax   (n*8*512*4B = 32 MB for n=2048; ws is ~1 GB)
    float* cand = (float*)d_ws;
    int*   cnt  = (int*)((char*)d_ws + (size_t)n * SLICES * SLICE_CAP * sizeof(float));
    float* smax = (float*)((char*)cnt + (size_t)n * SLICES * sizeof(int));

    hipMemsetAsync(out, 0, (size_t)out_size * sizeof(float), stream);
    k1_filter<<<n * SLICES, K1_BLOCK, 0, stream>>>(x, cand, cnt, smax, d, slice_len, ni);
    k2_solve<<<n, K2_BLOCK, 0, stream>>>(x, cand, cnt, smax, tgt, out, d, 1.0f / (float)n);
}